// Round 5
// baseline (90611.908 us; speedup 1.0000x reference)
//
#include <hip/hip_runtime.h>
#include <stddef.h>

// CFRMClassifier R5: register-resident GRU scan.
// 128 blocks = 32 groups x 4 slices; each block holds its 384KB w_hh slice in
// VGPRs (48 uint4/thread) and serves TWO chains (b=g, b=g+32) interleaved so
// each chain's LLC h-exchange hides behind the other chain's compute.
// Exchange = R4-validated relaxed agent atomics, single parallel round.

typedef unsigned short u16;
typedef short s8v __attribute__((ext_vector_type(8)));
typedef float f4v __attribute__((ext_vector_type(4)));

#define B_ 64
#define T_ 1024
#define H_ 512
#define G_ 1536
#define C_ 32
#define NCLS_ 1000
#define KCLS_ 16448

#define AGENT __HIP_MEMORY_SCOPE_AGENT

__device__ __forceinline__ u16 f2bf(float f) {
    unsigned u = __float_as_uint(f);
    unsigned r = (u + 0x7fffu + ((u >> 16) & 1u)) >> 16;
    return (u16)r;
}
__device__ __forceinline__ float b2f(u16 x) { return __uint_as_float(((unsigned)x) << 16); }
__device__ __forceinline__ float bflo(unsigned u) { return __uint_as_float(u << 16); }
__device__ __forceinline__ float bfhi(unsigned u) { return __uint_as_float(u & 0xffff0000u); }
__device__ __forceinline__ float sigmoidf_(float x) { return 1.0f / (1.0f + __expf(-x)); }
__device__ __forceinline__ float tanhf_(float x) { return 1.0f - 2.0f / (1.0f + __expf(2.0f * x)); }

// ---------- prep kernels ----------
__global__ void k_cast_wih(const float* __restrict__ src, u16* __restrict__ dst) {
    int i = blockIdx.x * 256 + threadIdx.x;
    if (i < G_ * H_) dst[i] = f2bf(src[i]);
}

// Register-resident pack. Thread tau of slice s holds wq[i4] (i4<48), component c.
// i = i4*4+c; m = i>>5 (row block), q = i&31 (k-pair); w = tau>>6 (k chunk), l = tau&63.
// row r = l + 64m -> j_row = (r>>7)*512 + s*128 + (r&127); k = 64w + 2q.
__global__ void k_pack_whhR(const float* __restrict__ w_hh, unsigned* __restrict__ wPv) {
    int idx = blockIdx.x * 256 + threadIdx.x;  // 4*48*512*4 = 393216
    if (idx >= 393216) return;
    int c = idx & 3;
    int rest = idx >> 2;
    int tau = rest & 511;
    int rest2 = rest >> 9;
    int i4 = rest2 % 48;
    int s = rest2 / 48;
    int i = i4 * 4 + c;
    int m = i >> 5, q = i & 31;
    int w = tau >> 6, l = tau & 63;
    int r = l + 64 * m;
    int j_row = (r >> 7) * 512 + s * 128 + (r & 127);
    int k = 64 * w + 2 * q;
    wPv[idx] = (unsigned)f2bf(w_hh[(size_t)j_row * H_ + k]) |
               ((unsigned)f2bf(w_hh[(size_t)j_row * H_ + k + 1]) << 16);
}

__global__ void k_decay(float* __restrict__ decay) {
    int t = blockIdx.x * 256 + threadIdx.x;
    if (t < T_) decay[t] = powf(0.85f, (float)(T_ - 1 - t));
}

__global__ void k_zero(float* __restrict__ p, int n) {
    int i = blockIdx.x * 256 + threadIdx.x;
    if (i < n) p[i] = 0.f;
}

// ---------- embedding gather + bf16 cast ----------
__global__ __launch_bounds__(256) void k_embed(const int* __restrict__ tokens,
                                               const float* __restrict__ emb,
                                               u16* __restrict__ X) {
    int g = blockIdx.x * 256 + threadIdx.x;
    int m = g >> 6, c8 = g & 63;
    int tok = tokens[m];
    const float4* src = (const float4*)(emb + (size_t)tok * H_ + c8 * 8);
    float4 f0 = src[0], f1 = src[1];
    uint4 pk;
    pk.x = (unsigned)f2bf(f0.x) | ((unsigned)f2bf(f0.y) << 16);
    pk.y = (unsigned)f2bf(f0.z) | ((unsigned)f2bf(f0.w) << 16);
    pk.z = (unsigned)f2bf(f1.x) | ((unsigned)f2bf(f1.y) << 16);
    pk.w = (unsigned)f2bf(f1.z) | ((unsigned)f2bf(f1.w) << 16);
    *(uint4*)(X + (size_t)m * H_ + c8 * 8) = pk;
}

// ---------- xp GEMM (bf16 MFMA) ----------
__global__ __launch_bounds__(256) void k_xp(const u16* __restrict__ X,
                                            const u16* __restrict__ Wih,
                                            const float* __restrict__ b_ih,
                                            u16* __restrict__ xp) {
    __shared__ u16 Bs[128 * 48];
    int tid = threadIdx.x;
    int bid = blockIdx.x;
    int m0 = (bid / 12) * 64;
    int n0 = (bid % 12) * 128;
    int w = tid >> 6, lane = tid & 63;
    int lm = lane & 15, q = lane >> 4;
    f4v acc[8];
#pragma unroll
    for (int i = 0; i < 8; i++) acc[i] = (f4v){0.f, 0.f, 0.f, 0.f};
    int arow = m0 + w * 16 + lm;
    const u16* Aptr = X + (size_t)arow * H_ + q * 8;
    int srow = tid >> 1, shalf = tid & 1;
    for (int kk = 0; kk < H_; kk += 32) {
        const uint4* src = (const uint4*)(Wih + (size_t)(n0 + srow) * H_ + kk + shalf * 16);
        uint4 v0 = src[0], v1 = src[1];
        uint4* dst = (uint4*)(Bs + srow * 48 + shalf * 16);
        dst[0] = v0; dst[1] = v1;
        __syncthreads();
        s8v a = *(const s8v*)(Aptr + kk);
#pragma unroll
        for (int nt = 0; nt < 8; nt++) {
            s8v bf = *(const s8v*)(Bs + (nt * 16 + lm) * 48 + q * 8);
            acc[nt] = __builtin_amdgcn_mfma_f32_16x16x32_bf16(a, bf, acc[nt], 0, 0, 0);
        }
        __syncthreads();
    }
#pragma unroll
    for (int nt = 0; nt < 8; nt++) {
        int col = n0 + nt * 16 + lm;
        float bias = b_ih[col];
#pragma unroll
        for (int r = 0; r < 4; r++) {
            int row = m0 + w * 16 + q * 4 + r;
            xp[(size_t)row * G_ + col] = f2bf(acc[nt][r] + bias);
        }
    }
}

// full 512-k dot contribution for this thread's 6 rows, h from LDS (wave-uniform)
__device__ __forceinline__ void dot6(const float* hl_, const uint4 (&wq)[48], int w,
                                     float (&acc)[6]) {
#pragma unroll
    for (int j = 0; j < 16; j++) {
        float4 h4 = ((const float4*)(hl_ + 64 * w))[j];
#pragma unroll
        for (int m = 0; m < 6; m++) {
            uint4 W = wq[m * 8 + (j >> 1)];
            unsigned u0 = (j & 1) ? W.z : W.x;
            unsigned u1 = (j & 1) ? W.w : W.y;
            acc[m] = fmaf(bflo(u0), h4.x, acc[m]);
            acc[m] = fmaf(bfhi(u0), h4.y, acc[m]);
            acc[m] = fmaf(bflo(u1), h4.z, acc[m]);
            acc[m] = fmaf(bfhi(u1), h4.w, acc[m]);
        }
    }
}

// ---------- register-resident dual-chain GRU scan ----------
// 128 blocks: s = x&3 (slice), g = x>>2 (group); chains bA=g, bB=g+32.
__global__ __launch_bounds__(512, 2) void k_scanR(const unsigned* __restrict__ wPvRaw,
                                                  const u16* __restrict__ xp,
                                                  const float* __restrict__ b_hh,
                                                  u16* __restrict__ hseq16,
                                                  float* __restrict__ hx,
                                                  unsigned* __restrict__ flags) {
    int x = blockIdx.x;
    int s = x & 3, g = x >> 2;
    int bA = g, bB = g + 32;
    int tid = threadIdx.x;
    int w = tid >> 6, l = tid & 63;
    __shared__ float hlA[512], hlB[512];
    __shared__ float part[3072];
    __shared__ float dots[384];

    uint4 wq[48];
    const uint4* wPv = (const uint4*)wPvRaw;
#pragma unroll
    for (int i4 = 0; i4 < 48; i4++) wq[i4] = wPv[(size_t)(s * 48 + i4) * 512 + tid];

    hlA[tid] = 0.f;
    hlB[tid] = 0.f;
    float bh = (tid < 384) ? b_hh[(tid >> 7) * H_ + s * 128 + (tid & 127)] : 0.f;
    int jo = s * 128 + (tid & 127);
    float hprevA = 0.f, hprevB = 0.f;
    const u16* xpA = xp + (size_t)bA * T_ * G_;
    const u16* xpB = xp + (size_t)bB * T_ * G_;
    unsigned* flgA = flags + bA * 64;
    unsigned* flgB = flags + bB * 64;
    int d = (tid - 128) >> 7;              // poller peer index 0..2 (tid>=128)
    int s2 = (s + 1 + d) & 3;
    int pj = s2 * 128 + ((tid - 128) & 127);
    __syncthreads();

    for (int p = 0; p < T_; p++) {
        // ======== chain A, step p ========
        if (p > 0 && tid == 0)
            __hip_atomic_store(flgB + s * 16, (unsigned)p, __ATOMIC_RELAXED, AGENT);
        u16 xr16 = 0, xz16 = 0, xn16 = 0;
        if (tid < 128) {
            const u16* xt = xpA + (size_t)p * G_;
            xr16 = xt[jo]; xz16 = xt[512 + jo]; xn16 = xt[1024 + jo];
        }
        {
            float acc[6] = {0.f, 0.f, 0.f, 0.f, 0.f, 0.f};
            dot6(hlA, wq, w, acc);
#pragma unroll
            for (int m = 0; m < 6; m++) part[w * 384 + l + 64 * m] = acc[m];
        }
        __syncthreads();
        if (tid < 384) {
            float sum = bh;
#pragma unroll
            for (int c = 0; c < 8; c++) sum += part[c * 384 + tid];
            dots[tid] = sum;
        }
        __syncthreads();
        if (tid < 128) {
            float r = sigmoidf_(b2f(xr16) + dots[tid]);
            float z = sigmoidf_(b2f(xz16) + dots[128 + tid]);
            float n = tanhf_(b2f(xn16) + r * dots[256 + tid]);
            float hn = (1.f - z) * n + z * hprevA;
            hprevA = hn;
            hlA[jo] = hn;
            __hip_atomic_store(hx + ((size_t)(((p + 1) & 1) * B_ + bA)) * 512 + jo, hn,
                               __ATOMIC_RELAXED, AGENT);
            hseq16[((size_t)p * B_ + bA) * H_ + jo] = f2bf(hn);
        } else if (p > 0) {
            const unsigned* fl = flgB + s2 * 16;
            while (__hip_atomic_load(fl, __ATOMIC_RELAXED, AGENT) < (unsigned)p) {}
            __asm__ __volatile__("" ::: "memory");
            hlB[pj] = __hip_atomic_load(
                hx + ((size_t)((p & 1) * B_ + bB)) * 512 + pj, __ATOMIC_RELAXED, AGENT);
        }
        __syncthreads();

        // ======== chain B, step p ========
        if (tid == 0)
            __hip_atomic_store(flgA + s * 16, (unsigned)(p + 1), __ATOMIC_RELAXED, AGENT);
        if (tid < 128) {
            const u16* xt = xpB + (size_t)p * G_;
            xr16 = xt[jo]; xz16 = xt[512 + jo]; xn16 = xt[1024 + jo];
        }
        {
            float acc[6] = {0.f, 0.f, 0.f, 0.f, 0.f, 0.f};
            dot6(hlB, wq, w, acc);
#pragma unroll
            for (int m = 0; m < 6; m++) part[w * 384 + l + 64 * m] = acc[m];
        }
        __syncthreads();
        if (tid < 384) {
            float sum = bh;
#pragma unroll
            for (int c = 0; c < 8; c++) sum += part[c * 384 + tid];
            dots[tid] = sum;
        }
        __syncthreads();
        if (tid < 128) {
            float r = sigmoidf_(b2f(xr16) + dots[tid]);
            float z = sigmoidf_(b2f(xz16) + dots[128 + tid]);
            float n = tanhf_(b2f(xn16) + r * dots[256 + tid]);
            float hn = (1.f - z) * n + z * hprevB;
            hprevB = hn;
            hlB[jo] = hn;
            __hip_atomic_store(hx + ((size_t)(((p + 1) & 1) * B_ + bB)) * 512 + jo, hn,
                               __ATOMIC_RELAXED, AGENT);
            hseq16[((size_t)p * B_ + bB) * H_ + jo] = f2bf(hn);
        } else if (p < T_ - 1) {
            const unsigned* fl = flgA + s2 * 16;
            while (__hip_atomic_load(fl, __ATOMIC_RELAXED, AGENT) < (unsigned)(p + 1)) {}
            __asm__ __volatile__("" ::: "memory");
            hlA[pj] = __hip_atomic_load(
                hx + ((size_t)((~p & 1) * B_ + bA)) * 512 + pj, __ATOMIC_RELAXED, AGENT);
        }
        __syncthreads();
    }
}

// ---------- decay-weighted & plain sums of h_seq (bf16), 8 t-chunks ----------
__global__ __launch_bounds__(512) void k_hw8(const u16* __restrict__ hseq16,
                                             const float* __restrict__ decay,
                                             float* __restrict__ hwT,
                                             float* __restrict__ hsumT) {
    int b = blockIdx.x & 63, chunk = blockIdx.x >> 6;
    int h = threadIdx.x;
    int t0 = chunk * 128;
    float aw = 0.f, as = 0.f;
    for (int tt = 0; tt < 128; tt++) {
        float v = b2f(hseq16[((size_t)(t0 + tt) * B_ + b) * H_ + h]);
        aw = fmaf(decay[t0 + tt], v, aw);
        as += v;
    }
    atomicAdd(&hwT[h * B_ + b], aw);
    atomicAdd(&hsumT[h * B_ + b], as);
}

// ---------- spreads, chunked over t (8 chunks) + atomicAdd ----------
__global__ __launch_bounds__(512) void k_sd8(const u16* __restrict__ hseq16,
                                             const float* __restrict__ ws,
                                             const float* __restrict__ bs,
                                             const float* __restrict__ decay,
                                             float* __restrict__ flatT) {
    int b = blockIdx.x & 63, chunk = blockIdx.x >> 6;
    int t0 = chunk * 128;
    int tid = threadIdx.x;
    __shared__ float hl[2][512];
    int c = tid >> 4, p = tid & 15;
    float wreg[32];
#pragma unroll
    for (int i = 0; i < 32; i++) wreg[i] = ws[c * H_ + p + 16 * i];
    float bsc = bs[c];
    float acc = 0.f;
    hl[0][tid] = b2f(hseq16[((size_t)t0 * B_ + b) * H_ + tid]);
    __syncthreads();
    for (int tt = 0; tt < 128; tt++) {
        float nxt = 0.f;
        if (tt < 127) nxt = b2f(hseq16[((size_t)(t0 + tt + 1) * B_ + b) * H_ + tid]);
        int pg = tt & 1;
        float partial = 0.f;
#pragma unroll
        for (int i = 0; i < 32; i++) partial = fmaf(wreg[i], hl[pg][p + 16 * i], partial);
        partial += __shfl_xor(partial, 1, 16);
        partial += __shfl_xor(partial, 2, 16);
        partial += __shfl_xor(partial, 4, 16);
        partial += __shfl_xor(partial, 8, 16);
        acc = fmaf(decay[t0 + tt], sigmoidf_(partial + bsc), acc);
        __syncthreads();
        hl[pg ^ 1][tid] = nxt;
        __syncthreads();
    }
    if (p == 0) atomicAdd(&flatT[(c * 514 + 512) * B_ + b], 0.15f * acc);
}

// ---------- weights -> softmax -> nw rows ----------
__global__ __launch_bounds__(1024) void k_weights(const float* __restrict__ hsumT,
                                                  const float* __restrict__ ww,
                                                  const float* __restrict__ bw,
                                                  float* __restrict__ flatT) {
    int tid = threadIdx.x;
    __shared__ float wmat[C_ * B_];
    __shared__ float mb[B_], sb[B_];
    int b = tid & 63;
    int c0 = tid >> 6;
    float a0 = 0.f, a1 = 0.f;
    for (int h = 0; h < H_; h++) {
        float hv = hsumT[h * B_ + b];
        a0 = fmaf(ww[c0 * H_ + h], hv, a0);
        a1 = fmaf(ww[(c0 + 16) * H_ + h], hv, a1);
    }
    wmat[c0 * B_ + b] = a0 + 1024.0f * bw[c0];
    wmat[(c0 + 16) * B_ + b] = a1 + 1024.0f * bw[c0 + 16];
    __syncthreads();
    if (tid < 64) {
        float m = -1e30f;
        for (int c = 0; c < C_; c++) m = fmaxf(m, wmat[c * B_ + tid]);
        float sum = 0.f;
        for (int c = 0; c < C_; c++) sum += __expf(wmat[c * B_ + tid] - m);
        mb[tid] = m;
        sb[tid] = 1.0f / sum;
    }
    __syncthreads();
    flatT[(c0 * 514 + 513) * B_ + b] = __expf(wmat[c0 * B_ + b] - mb[b]) * sb[b];
    flatT[((c0 + 16) * 514 + 513) * B_ + b] = __expf(wmat[(c0 + 16) * B_ + b] - mb[b]) * sb[b];
}

// ---------- centers rows ----------
__global__ __launch_bounds__(64) void k_centersT(const float* __restrict__ hwT,
                                                 const float* __restrict__ wc,
                                                 const float* __restrict__ bc,
                                                 float* __restrict__ flatT) {
    int b = threadIdx.x;
    int k0 = blockIdx.x * 8;
    float acc[8] = {0, 0, 0, 0, 0, 0, 0, 0};
    for (int h = 0; h < H_; h++) {
        float hv = hwT[h * B_ + b];
#pragma unroll
        for (int r = 0; r < 8; r++) acc[r] = fmaf(wc[(size_t)(k0 + r) * H_ + h], hv, acc[r]);
    }
#pragma unroll
    for (int r = 0; r < 8; r++) {
        int k = k0 + r;
        int c = k >> 9, i = k & 511;
        flatT[(c * 514 + i) * B_ + b] = 0.15f * (acc[r] + (1.0f / 0.15f) * bc[k]);
    }
}

// ---------- classifier ----------
__global__ __launch_bounds__(256) void k_cls(const float* __restrict__ flatT,
                                             const float* __restrict__ wcls,
                                             const float* __restrict__ bcls,
                                             float* __restrict__ out) {
    int tid = threadIdx.x;
    int wv = tid >> 6, b = tid & 63;
    int j0 = blockIdx.x * 8;
    __shared__ float red[4][8][64];
    float acc[8] = {0, 0, 0, 0, 0, 0, 0, 0};
    for (int i = 0; i < 4112; i++) {
        int k = wv * 4112 + i;
        float fv = flatT[k * B_ + b];
#pragma unroll
        for (int r = 0; r < 8; r++) acc[r] = fmaf(wcls[(size_t)(j0 + r) * KCLS_ + k], fv, acc[r]);
    }
#pragma unroll
    for (int r = 0; r < 8; r++) red[wv][r][b] = acc[r];
    __syncthreads();
    for (int rr = tid; rr < 512; rr += 256) {
        int r = rr >> 6, bb = rr & 63;
        float sum = red[0][r][bb] + red[1][r][bb] + red[2][r][bb] + red[3][r][bb];
        out[bb * NCLS_ + j0 + r] = sum + bcls[j0 + r];
    }
}

extern "C" void kernel_launch(void* const* d_in, const int* in_sizes, int n_in,
                              void* d_out, int out_size, void* d_ws, size_t ws_size,
                              hipStream_t stream) {
    const int*   tokens = (const int*)d_in[0];
    const float* emb    = (const float*)d_in[1];
    const float* w_ih   = (const float*)d_in[2];
    const float* w_hh   = (const float*)d_in[3];
    const float* b_ih   = (const float*)d_in[4];
    const float* b_hh   = (const float*)d_in[5];
    const float* wc     = (const float*)d_in[6];
    const float* bc     = (const float*)d_in[7];
    const float* ws     = (const float*)d_in[8];
    const float* bs     = (const float*)d_in[9];
    const float* ww     = (const float*)d_in[10];
    const float* bw     = (const float*)d_in[11];
    const float* wcls   = (const float*)d_in[12];
    const float* bcls   = (const float*)d_in[13];
    float* out = (float*)d_out;

    char* w = (char*)d_ws;
    u16*      xp     = (u16*)(w + 0);                 // 201,326,592
    u16*      hseq16 = (u16*)(w + 201326592);         //  67,108,864 (bf16 now)
    u16*      X16    = (u16*)(w + 335544320);         //  67,108,864 (dead after k_xp)
    u16*      Wih16  = (u16*)(w + 402653184);         //   1,572,864
    unsigned* wPv    = (unsigned*)(w + 404226048);    //   1,572,864 (4*48*512*4 u32)
    float*    decay  = (float*)(w + 405798912);       //       4,096
    float*    hwT    = (float*)(w + 405803008);       //     131,072
    float*    hsumT  = (float*)(w + 405934080);       //     131,072
    float*    flatT  = (float*)(w + 406065152);       //   4,210,688
    // aliased into X16's region after k_xp:
    float*    hx     = (float*)(w + 335544320);              // 2*64*512*4 = 262,144
    unsigned* flags  = (unsigned*)(w + 335544320 + 262144);  // 64*64*4    =  16,384

    k_cast_wih<<<dim3((G_ * H_ + 255) / 256), dim3(256), 0, stream>>>(w_ih, Wih16);
    k_pack_whhR<<<dim3(1536), dim3(256), 0, stream>>>(w_hh, wPv);
    k_decay<<<dim3(4), dim3(256), 0, stream>>>(decay);
    k_zero<<<dim3((1118208 + 255) / 256), dim3(256), 0, stream>>>(hwT, 1118208);
    k_embed<<<dim3(16384), dim3(256), 0, stream>>>(tokens, emb, X16);
    k_xp<<<dim3(12288), dim3(256), 0, stream>>>(X16, Wih16, b_ih, xp);
    k_zero<<<dim3(16), dim3(256), 0, stream>>>((float*)flags, 4096);  // after k_xp (aliases X16)
    k_scanR<<<dim3(128), dim3(512), 0, stream>>>(wPv, xp, b_hh, hseq16, hx, flags);
    k_hw8<<<dim3(512), dim3(512), 0, stream>>>(hseq16, decay, hwT, hsumT);
    k_sd8<<<dim3(512), dim3(512), 0, stream>>>(hseq16, ws, bs, decay, flatT);
    k_weights<<<dim3(1), dim3(1024), 0, stream>>>(hsumT, ww, bw, flatT);
    k_centersT<<<dim3(2048), dim3(64), 0, stream>>>(hwT, wc, bc, flatT);
    k_cls<<<dim3(125), dim3(256), 0, stream>>>(flatT, wcls, bcls, out);
}